// Round 2
// 74.981 us; speedup vs baseline: 1.1506x; 1.1506x over previous
//
#include <hip/hip_runtime.h>

#define NROWS 8192
#define DIM 256
#define NCLS 100
#define NCLS_PAD 128
#define TEMP 0.7f
#define EPSV 1e-8f
#define LMAX 512  // max rows/class (mean 82, multinomial tail << 512)

typedef __attribute__((ext_vector_type(8))) short short8;
typedef __attribute__((ext_vector_type(4))) float f32x4;

// fp32 -> bf16 bits, round-to-nearest-even
static __device__ __forceinline__ unsigned short f2bf(float x) {
    unsigned u = __builtin_bit_cast(unsigned, x);
    return (unsigned short)((u + 0x7FFFu + ((u >> 16) & 1u)) >> 16);
}

// ---------------- kernel 1: prototype build -> bf16 protoB = mean/(|mean|*T) -------
// one block per padded class; 512 threads: batched label scan (16 preloaded/thread),
// gather split over 8 groups of 64 with 4-deep pipelined b128 loads.
__global__ __launch_bounds__(512) void k_proto(const float* __restrict__ f,
                                               const int* __restrict__ labels,
                                               unsigned short* __restrict__ protoB,
                                               float* __restrict__ countf,
                                               float* __restrict__ out) {
    int c = blockIdx.x, tid = threadIdx.x;
    __shared__ int list[LMAX];
    __shared__ int nm;
    __shared__ float4 red4[512];
    if (tid == 0) nm = 0;
    __syncthreads();
    int lv[16];
    #pragma unroll
    for (int i = 0; i < 16; ++i) lv[i] = labels[i * 512 + tid];  // one latency wait
    #pragma unroll
    for (int i = 0; i < 16; ++i)
        if (lv[i] == c) {
            int idx = atomicAdd(&nm, 1);  // LDS atomic
            if (idx < LMAX) list[idx] = i * 512 + tid;
        }
    __syncthreads();
    int n = nm < LMAX ? nm : LMAX;
    int g = tid >> 6, d = tid & 63;  // 8 groups; group g takes i == g (mod 8)
    float4 acc = make_float4(0.f, 0.f, 0.f, 0.f);
    int i = g;
    for (; i + 32 <= n; i += 32) {  // 4-deep MLP of b128 loads
        float4 v0 = *(const float4*)&f[list[i +  0] * DIM + d * 4];
        float4 v1 = *(const float4*)&f[list[i +  8] * DIM + d * 4];
        float4 v2 = *(const float4*)&f[list[i + 16] * DIM + d * 4];
        float4 v3 = *(const float4*)&f[list[i + 24] * DIM + d * 4];
        acc.x += (v0.x + v1.x) + (v2.x + v3.x);
        acc.y += (v0.y + v1.y) + (v2.y + v3.y);
        acc.z += (v0.z + v1.z) + (v2.z + v3.z);
        acc.w += (v0.w + v1.w) + (v2.w + v3.w);
    }
    for (; i + 16 <= n; i += 16) {  // 2-deep
        float4 v0 = *(const float4*)&f[list[i + 0] * DIM + d * 4];
        float4 v1 = *(const float4*)&f[list[i + 8] * DIM + d * 4];
        acc.x += v0.x + v1.x; acc.y += v0.y + v1.y;
        acc.z += v0.z + v1.z; acc.w += v0.w + v1.w;
    }
    for (; i < n; i += 8) {
        float4 v = *(const float4*)&f[list[i] * DIM + d * 4];
        acc.x += v.x; acc.y += v.y; acc.z += v.z; acc.w += v.w;
    }
    red4[tid] = acc;
    __syncthreads();
    if (tid < 64) {  // wave 0 finishes: combine 8 groups, mean, norm, write bf16
        float4 s = red4[d];
        #pragma unroll
        for (int k = 1; k < 8; ++k) {
            float4 t = red4[d + 64 * k];
            s.x += t.x; s.y += t.y; s.z += t.z; s.w += t.w;
        }
        float invn = 1.0f / fmaxf((float)n, 1.0f);
        float mx = s.x * invn, my = s.y * invn, mz = s.z * invn, mw = s.w * invn;
        float ssq = mx * mx + my * my + mz * mz + mw * mw;
        #pragma unroll
        for (int m = 32; m > 0; m >>= 1) ssq += __shfl_xor(ssq, m);
        float scale = 1.0f / (fmaxf(sqrtf(ssq), EPSV) * TEMP);
        ushort4 o;
        o.x = f2bf(mx * scale);
        o.y = f2bf(my * scale);
        o.z = f2bf(mz * scale);
        o.w = f2bf(mw * scale);
        *(ushort4*)&protoB[c * DIM + d * 4] = o;  // padded classes: zeros
        if (d == 0) {
            countf[c] = (float)n;
            if (c == NCLS_PAD - 1) out[0] = 0.0f;  // init for k_main's atomic
        }
    }
}

// ---------------- kernel 2: MFMA dots + contrastive reduction ------
// 512 blocks x 256 thr (4 waves): block = 16 rows x 128 classes, A tile staged to
// LDS as bf16 (XOR-swizzled, sumsq folded in), each wave takes 2 class-tiles.
// 2048 waves (8/CU) vs 512 before: latency hiding instead of exposed L3/HBM stalls.
__global__ __launch_bounds__(256) void k_main(const float* __restrict__ f,
                                              const int* __restrict__ labels,
                                              const unsigned short* __restrict__ protoB,
                                              const float* __restrict__ countf,
                                              float* __restrict__ out) {
    int tid = threadIdx.x;
    int rb = blockIdx.x * 16;
    __shared__ unsigned short As[16 * DIM];  // 8 KB bf16 A tile, XOR-swizzled rows
    __shared__ float invfS[16];
    __shared__ float dgS[16];
    __shared__ float wsum[4][16];
    char* asb = (char*)As;

    {   // stage: thread covers row=tid>>4, 16 floats at cols (s+16i)*4
        int row = tid >> 4, s = tid & 15;
        const float* fr = f + (rb + row) * DIM;
        float4 v[4];
        #pragma unroll
        for (int i = 0; i < 4; ++i) v[i] = *(const float4*)(fr + (s + 16 * i) * 4);
        float ss = 0.f;
        #pragma unroll
        for (int i = 0; i < 4; ++i) {
            ss += v[i].x * v[i].x + v[i].y * v[i].y + v[i].z * v[i].z + v[i].w * v[i].w;
            ushort4 o;
            o.x = f2bf(v[i].x); o.y = f2bf(v[i].y); o.z = f2bf(v[i].z); o.w = f2bf(v[i].w);
            int byte = (row * 512 + s * 8 + i * 128) ^ ((row & 7) << 4);  // G4 swizzle
            *(ushort4*)(asb + byte) = o;
        }
        ss += __shfl_xor(ss, 1); ss += __shfl_xor(ss, 2);
        ss += __shfl_xor(ss, 4); ss += __shfl_xor(ss, 8);
        if (s == 0) invfS[row] = 1.0f / fmaxf(sqrtf(ss), EPSV);
    }
    __syncthreads();

    int w = tid >> 6, l = tid & 63;
    int n16 = l & 15, q = l >> 4;
    f32x4 acc0 = {0.f, 0.f, 0.f, 0.f}, acc1 = {0.f, 0.f, 0.f, 0.f};
    // B-frag: class = t*16+n16, k = kc + q*8 + j ; wave w owns tiles 2w, 2w+1
    const unsigned short* pb0 = protoB + ((2 * w)     * 16 + n16) * DIM + q * 8;
    const unsigned short* pb1 = protoB + ((2 * w + 1) * 16 + n16) * DIM + q * 8;
    // A-frag: row = n16, k = kc + q*8 + j  (m89/m120-verified lane map)
    int arow = n16 * 512 + q * 16;
    int swz  = (n16 & 7) << 4;
    #pragma unroll
    for (int kc = 0; kc < DIM; kc += 32) {
        short8 af = *(const short8*)(asb + ((arow + kc * 2) ^ swz));
        short8 b0 = *(const short8*)(pb0 + kc);
        short8 b1 = *(const short8*)(pb1 + kc);
        acc0 = __builtin_amdgcn_mfma_f32_16x16x32_bf16(af, b0, acc0, 0, 0, 0);
        acc1 = __builtin_amdgcn_mfma_f32_16x16x32_bf16(af, b1, acc1, 0, 0, 0);
    }

    // C/D map: row = q*4 + reg, col = n16 + 16t
    int lab4[4];
    float inv4[4];
    #pragma unroll
    for (int j = 0; j < 4; ++j) {
        lab4[j] = labels[rb + q * 4 + j];
        inv4[j] = invfS[q * 4 + j];
    }
    int col0 = n16 + 16 * (2 * w);
    int col1 = col0 + 16;
    float cf0 = countf[col0], cf1 = countf[col1];  // padded classes: 0
    float rp[4];
    #pragma unroll
    for (int j = 0; j < 4; ++j) {
        float a0 = acc0[j] * inv4[j];  // sim/T
        float a1 = acc1[j] * inv4[j];
        rp[j] = cf0 * __expf(a0) + cf1 * __expf(a1);
        if (col0 == lab4[j]) dgS[q * 4 + j] = a0;  // unique writer per row
        if (col1 == lab4[j]) dgS[q * 4 + j] = a1;
    }
    #pragma unroll
    for (int m = 1; m <= 8; m <<= 1) {  // sum this wave's 32 cols across 16 lanes
        #pragma unroll
        for (int j = 0; j < 4; ++j) rp[j] += __shfl_xor(rp[j], m);
    }
    if (n16 == 0) {
        #pragma unroll
        for (int j = 0; j < 4; ++j) wsum[w][q * 4 + j] = rp[j];
    }
    __syncthreads();
    if (tid < 16) {  // combine 4 wave partials, log, block-reduce, one atomic
        float tot = wsum[0][tid] + wsum[1][tid] + wsum[2][tid] + wsum[3][tid];
        float v = __logf(tot) - dgS[tid];
        v += __shfl_xor(v, 1); v += __shfl_xor(v, 2);
        v += __shfl_xor(v, 4); v += __shfl_xor(v, 8);
        if (tid == 0) atomicAdd(out, v * (1.0f / (float)NROWS));
    }
}

// ---------------- launch: 2 dispatches, no memsets ----------------
// ws: [0, 64 KB) protoB bf16 | floats at offset 16384: countf[128]
extern "C" void kernel_launch(void* const* d_in, const int* in_sizes, int n_in,
                              void* d_out, int out_size, void* d_ws, size_t ws_size,
                              hipStream_t stream) {
    const float* f      = (const float*)d_in[0];
    const int*   labels = (const int*)d_in[1];
    unsigned short* protoB = (unsigned short*)d_ws;
    float* countf          = (float*)d_ws + 16384;

    k_proto<<<NCLS_PAD, 512, 0, stream>>>(f, labels, protoB, countf, (float*)d_out);
    k_main<<<NROWS / 16, 256, 0, stream>>>(f, labels, protoB, countf, (float*)d_out);
}